// Round 6
// baseline (241.804 us; speedup 1.0000x reference)
//
#include <hip/hip_runtime.h>
#include <hip/hip_bf16.h>

#define N_ENT    100000
#define NUM_REL  400
#define DIM      128
#define NUM_EDGES 800000
#define E_HALF   400000
#define N_RB     6250          // N_ENT/16 rowblocks

using short8 = __attribute__((ext_vector_type(8))) short;
using f32x4  = __attribute__((ext_vector_type(4))) float;

__device__ __forceinline__ float bf_lo(unsigned u) { return __uint_as_float(u << 16); }
__device__ __forceinline__ float bf_hi(unsigned u) { return __uint_as_float(u & 0xffff0000u); }
__device__ __forceinline__ unsigned short f2bf(float f) {
    unsigned u = __float_as_uint(f);
    u = u + 0x7fffu + ((u >> 16) & 1u);   // RNE
    return (unsigned short)(u >> 16);
}
__device__ __forceinline__ unsigned pack2bf(float a, float b) {
    return (unsigned)f2bf(a) | ((unsigned)f2bf(b) << 16);
}

// ---------------- deg histogram ----------------
__global__ __launch_bounds__(256) void deg_kernel(const int* __restrict__ rows,
                                                  int* __restrict__ deg) {
    int e = blockIdx.x * 256 + threadIdx.x;
    if (e >= NUM_EDGES) return;
    int half = (e >= E_HALF) ? 1 : 0;
    atomicAdd(&deg[half * N_ENT + rows[e]], 1);
}

// ---------------- deg -> dinv ----------------
__global__ __launch_bounds__(256) void dinv_kernel(const int* __restrict__ deg,
                                                   float* __restrict__ dinv) {
    int i = blockIdx.x * 256 + threadIdx.x;
    if (i >= 2 * N_ENT) return;
    int d = deg[i];
    dinv[i] = (d > 0) ? rsqrtf((float)d) : 0.0f;
}

// ---------------- segment offsets via wave-atomic allocation ----------------
__global__ __launch_bounds__(256) void offs_kernel(const int* __restrict__ deg,
                                                   int* __restrict__ offs,
                                                   int* __restrict__ counter) {
    int i = blockIdx.x * 256 + threadIdx.x;
    int lane = threadIdx.x & 63;
    int v = (i < 2 * N_ENT) ? deg[i] : 0;
    int pre = v;
    #pragma unroll
    for (int d = 1; d < 64; d <<= 1) {
        int t = __shfl_up(pre, d);
        if (lane >= d) pre += t;
    }
    int total = __shfl(pre, 63);
    int base = 0;
    if (lane == 0) base = atomicAdd(counter, total);
    base = __shfl(base, 0);
    if (i < 2 * N_ENT) offs[i] = base + pre - v;
}

// ---------------- fill CSR records {col|t<<17, norm} ----------------
__global__ __launch_bounds__(256) void fill_kernel(const int* __restrict__ rows,
                                                   const int* __restrict__ cols,
                                                   const int* __restrict__ et,
                                                   const float* __restrict__ dinv,
                                                   const int* __restrict__ offs,
                                                   int* __restrict__ cursor,
                                                   uint2* __restrict__ recs) {
    int e = blockIdx.x * 256 + threadIdx.x;
    if (e >= NUM_EDGES) return;
    int half = (e >= E_HALF) ? 1 : 0;
    int g = half * N_ENT + rows[e];
    int col = cols[e];
    int t = et[e];
    int pos = atomicAdd(&cursor[g], 1);
    float norm = dinv[g] * dinv[half * N_ENT + col];
    recs[offs[g] + pos] = make_uint2((unsigned)col | ((unsigned)t << 17),
                                     __float_as_uint(norm));
}

// ---------------- prep: xb = bf16(x), row-major ----------------
__global__ __launch_bounds__(256) void prep_x_kernel(const float* __restrict__ x,
                                                     uint4* __restrict__ xb4) {
    int j = blockIdx.x * 256 + threadIdx.x;
    if (j >= N_ENT * 16) return;
    const float* p = x + (size_t)(j >> 4) * DIM + (j & 15) * 8;
    float4 f0 = *(const float4*)p;
    float4 f1 = *(const float4*)(p + 4);
    uint4 o;
    o.x = pack2bf(f0.x, f0.y);
    o.y = pack2bf(f0.z, f0.w);
    o.z = pack2bf(f1.x, f1.y);
    o.w = pack2bf(f1.z, f1.w);
    xb4[j] = o;
}

// ---------------- prep: wtfrag (B in MFMA fragment order) ; rb16 = bf16(r) ----------------
// wtfrag u4 index: ((nblk*12 + kb)*64 + lane); lane=(ks*16+lr): n=nblk*16+lr, k=kb*32+ks*8+e
__global__ __launch_bounds__(256) void prep_wr_kernel(const float* __restrict__ w_in,
                                                      const float* __restrict__ w_out,
                                                      const float* __restrict__ w_loop,
                                                      const float* __restrict__ r,
                                                      uint4* __restrict__ wtfrag,
                                                      uint4* __restrict__ rb16) {
    int i = blockIdx.x * 256 + threadIdx.x;
    if (i < 8 * 12 * 64) {
        int lane = i & 63;
        int kb = (i >> 6) % 12;
        int nblk = i / 768;
        int n = nblk * 16 + (lane & 15);
        int s = kb >> 2;
        int klo = (kb & 3) * 32 + (lane >> 4) * 8;    // 0..127 within slice
        const float* W = (s == 0) ? w_in : (s == 1) ? w_out : w_loop;
        float v[8];
        #pragma unroll
        for (int e = 0; e < 8; ++e) v[e] = W[(klo + e) * DIM + n];
        uint4 o;
        o.x = pack2bf(v[0], v[1]);
        o.y = pack2bf(v[2], v[3]);
        o.z = pack2bf(v[4], v[5]);
        o.w = pack2bf(v[6], v[7]);
        wtfrag[i] = o;
    } else {
        int j = i - 8 * 12 * 64;
        if (j < NUM_REL * 16) {
            const float* p = r + (size_t)(j >> 4) * DIM + (j & 15) * 8;
            float4 f0 = *(const float4*)p;
            float4 f1 = *(const float4*)(p + 4);
            uint4 o;
            o.x = pack2bf(f0.x, f0.y);
            o.y = pack2bf(f0.z, f0.w);
            o.z = pack2bf(f1.x, f1.y);
            o.w = pack2bf(f1.z, f1.w);
            rb16[j] = o;
        }
    }
}

// ---------------- cvec = loop_rel @ w_loop (128 f32) ----------------
__global__ __launch_bounds__(128) void cvec_kernel(const float* __restrict__ loop_rel,
                                                   const float* __restrict__ w_loop,
                                                   float* __restrict__ cvec) {
    int j = threadIdx.x;
    float acc = 0.0f;
    #pragma unroll 8
    for (int k = 0; k < DIM; ++k)
        acc += loop_rel[k] * w_loop[k * DIM + j];
    cvec[j] = acc;
}

// ---------------- gather-aggregate -> aggfrag (MFMA fragment order) ----------------
#define ACC8(X, V, NRM)                                        \
    acc[0] += (NRM) * (bf_lo((X).x) - bf_lo((V).x));           \
    acc[1] += (NRM) * (bf_hi((X).x) - bf_hi((V).x));           \
    acc[2] += (NRM) * (bf_lo((X).y) - bf_lo((V).y));           \
    acc[3] += (NRM) * (bf_hi((X).y) - bf_hi((V).y));           \
    acc[4] += (NRM) * (bf_lo((X).z) - bf_lo((V).z));           \
    acc[5] += (NRM) * (bf_hi((X).z) - bf_hi((V).z));           \
    acc[6] += (NRM) * (bf_lo((X).w) - bf_lo((V).w));           \
    acc[7] += (NRM) * (bf_hi((X).w) - bf_hi((V).w));

__global__ __launch_bounds__(256) void gather_agg_kernel(const int* __restrict__ offs,
                                                         const int* __restrict__ deg,
                                                         const uint2* __restrict__ recs,
                                                         const unsigned short* __restrict__ xb,
                                                         const unsigned short* __restrict__ rb16,
                                                         uint4* __restrict__ aggfrag) {
    int gid = blockIdx.x * 256 + threadIdx.x;
    int g = gid >> 4;
    if (g >= 2 * N_ENT) return;
    int c = gid & 15;                    // lane covers 16 B = 8 bf16 (k = c*8..c*8+7)
    int e = offs[g];
    int end = e + deg[g];
    float acc[8] = {0.f, 0.f, 0.f, 0.f, 0.f, 0.f, 0.f, 0.f};
    for (; e + 4 <= end; e += 4) {
        uint2 r0 = recs[e];
        uint2 r1 = recs[e + 1];
        uint2 r2 = recs[e + 2];
        uint2 r3 = recs[e + 3];
        uint4 x0 = ((const uint4*)(xb + (size_t)(r0.x & 0x1ffff) * DIM))[c];
        uint4 v0 = ((const uint4*)(rb16 + (size_t)(r0.x >> 17) * DIM))[c];
        uint4 x1 = ((const uint4*)(xb + (size_t)(r1.x & 0x1ffff) * DIM))[c];
        uint4 v1 = ((const uint4*)(rb16 + (size_t)(r1.x >> 17) * DIM))[c];
        uint4 x2 = ((const uint4*)(xb + (size_t)(r2.x & 0x1ffff) * DIM))[c];
        uint4 v2 = ((const uint4*)(rb16 + (size_t)(r2.x >> 17) * DIM))[c];
        uint4 x3 = ((const uint4*)(xb + (size_t)(r3.x & 0x1ffff) * DIM))[c];
        uint4 v3 = ((const uint4*)(rb16 + (size_t)(r3.x >> 17) * DIM))[c];
        float n0 = __uint_as_float(r0.y);
        float n1 = __uint_as_float(r1.y);
        float n2 = __uint_as_float(r2.y);
        float n3 = __uint_as_float(r3.y);
        ACC8(x0, v0, n0)
        ACC8(x1, v1, n1)
        ACC8(x2, v2, n2)
        ACC8(x3, v3, n3)
    }
    for (; e < end; ++e) {
        uint2 rA = recs[e];
        uint4 xA = ((const uint4*)(xb + (size_t)(rA.x & 0x1ffff) * DIM))[c];
        uint4 vA = ((const uint4*)(rb16 + (size_t)(rA.x >> 17) * DIM))[c];
        float nA = __uint_as_float(rA.y);
        ACC8(xA, vA, nA)
    }
    uint4 o;
    o.x = pack2bf(acc[0], acc[1]);
    o.y = pack2bf(acc[2], acc[3]);
    o.z = pack2bf(acc[4], acc[5]);
    o.w = pack2bf(acc[6], acc[7]);
    // fragment-order store: rowblk=g>>4, kq=c>>2, ksub=c&3, lr=g&15
    aggfrag[(((g >> 4) * 4 + (c >> 2)) * 64) + (c & 3) * 16 + (g & 15)] = o;
}

// ---------------- MFMA GEMM, fragment-direct, no LDS, no barriers ----------------
// out = tanh((aggA@Win + aggB@Wout + x@Wloop - cvec)/3 + bias)
// M=100000, N=128, K=384. 128 rows/block, 4 waves 2x2 (64x64 each).
__global__ __launch_bounds__(256) void mfma_gemm_kernel(const uint4* __restrict__ aggfrag,
                                                        const float* __restrict__ x,
                                                        const uint4* __restrict__ wtfrag,
                                                        const float* __restrict__ bias,
                                                        const float* __restrict__ cvec,
                                                        float* __restrict__ out) {
    int tid = threadIdx.x;
    int wave = tid >> 6;
    int lane = tid & 63;
    int wm = wave >> 1, wn = wave & 1;
    int lr = lane & 15;
    int ks = lane >> 4;                    // 0..3
    int rbb = blockIdx.x * 8 + wm * 4;     // rowblk base for this wave

    f32x4 acc[4][4];
    #pragma unroll
    for (int mi = 0; mi < 4; ++mi)
        #pragma unroll
        for (int ni = 0; ni < 4; ++ni)
            acc[mi][ni] = (f32x4){0.f, 0.f, 0.f, 0.f};

    #pragma unroll
    for (int kb = 0; kb < 12; ++kb) {
        int s = kb >> 2, kq = kb & 3;
        short8 a[4], b[4];
        #pragma unroll
        for (int ni = 0; ni < 4; ++ni) {
            uint4 u = wtfrag[((wn * 4 + ni) * 12 + kb) * 64 + lane];
            b[ni] = *(short8*)&u;
        }
        if (s < 2) {
            #pragma unroll
            for (int mi = 0; mi < 4; ++mi) {
                int rb = rbb + mi;
                if (rb > N_RB - 1) rb = N_RB - 1;
                rb += s * N_RB;
                uint4 u = aggfrag[((size_t)rb * 4 + kq) * 64 + lane];
                a[mi] = *(short8*)&u;
            }
        } else {
            #pragma unroll
            for (int mi = 0; mi < 4; ++mi) {
                int row = (rbb + mi) * 16 + lr;
                if (row > N_ENT - 1) row = N_ENT - 1;
                const float* xp = x + (size_t)row * DIM + kq * 32 + ks * 8;
                float4 f0 = *(const float4*)xp;
                float4 f1 = *(const float4*)(xp + 4);
                uint4 u;
                u.x = pack2bf(f0.x, f0.y);
                u.y = pack2bf(f0.z, f0.w);
                u.z = pack2bf(f1.x, f1.y);
                u.w = pack2bf(f1.z, f1.w);
                a[mi] = *(short8*)&u;
            }
        }
        #pragma unroll
        for (int mi = 0; mi < 4; ++mi)
            #pragma unroll
            for (int ni = 0; ni < 4; ++ni)
                acc[mi][ni] = __builtin_amdgcn_mfma_f32_16x16x32_bf16(a[mi], b[ni], acc[mi][ni], 0, 0, 0);
    }

    int col0 = wn * 64;
    int row0w = blockIdx.x * 128 + wm * 64;
    const float third = 1.0f / 3.0f;
    float bb[4];
    #pragma unroll
    for (int ni = 0; ni < 4; ++ni) {
        int col = col0 + ni * 16 + lr;
        bb[ni] = bias[col] - third * cvec[col];
    }

    #pragma unroll
    for (int mi = 0; mi < 4; ++mi) {
        #pragma unroll
        for (int reg = 0; reg < 4; ++reg) {
            int grow = row0w + mi * 16 + ks * 4 + reg;
            if (grow < N_ENT) {
                #pragma unroll
                for (int ni = 0; ni < 4; ++ni)
                    out[(size_t)grow * DIM + col0 + ni * 16 + lr] =
                        tanhf(acc[mi][ni][reg] * third + bb[ni]);
            }
        }
    }
}

// ---------------- r_out = r @ w_rel  (400x128 @ 128x128, f32) ----------------
__global__ __launch_bounds__(128) void rel_gemm_kernel(const float* __restrict__ r,
                                                       const float* __restrict__ w_rel,
                                                       float* __restrict__ r_out) {
    __shared__ float rrow[128];
    int i = blockIdx.x;
    int j = threadIdx.x;
    rrow[j] = r[i * DIM + j];
    __syncthreads();
    float acc = 0.0f;
    #pragma unroll 8
    for (int k = 0; k < DIM; ++k)
        acc += rrow[k] * w_rel[k * DIM + j];
    r_out[i * DIM + j] = acc;
}

extern "C" void kernel_launch(void* const* d_in, const int* in_sizes, int n_in,
                              void* d_out, int out_size, void* d_ws, size_t ws_size,
                              hipStream_t stream) {
    const float* x        = (const float*)d_in[0];
    const float* r        = (const float*)d_in[1];
    const int*   ei       = (const int*)d_in[2];   // [2][800000]: rows then cols
    const int*   et       = (const int*)d_in[3];
    const float* w_in     = (const float*)d_in[4];
    const float* w_out    = (const float*)d_in[5];
    const float* w_loop   = (const float*)d_in[6];
    const float* w_rel    = (const float*)d_in[7];
    const float* loop_rel = (const float*)d_in[8];
    const float* bias     = (const float*)d_in[9];

    float* out   = (float*)d_out;            // 100000*128
    float* r_out = out + (size_t)N_ENT * DIM;

    // -------- workspace layout --------
    unsigned short* aggf = (unsigned short*)d_ws;            // [2N*128] bf16 frag-order
    unsigned short* xb   = aggf + 2ull * N_ENT * DIM;        // [N][128] bf16 row-major
    unsigned short* wtf  = xb + (size_t)N_ENT * DIM;         // 8*12*64*8 bf16 frag-order
    unsigned short* rb16 = wtf + 8 * 12 * 64 * 8;            // [400][128] bf16
    uint2* recs = (uint2*)(rb16 + NUM_REL * DIM);            // 800k x 8 B
    int*   deg     = (int*)(recs + NUM_EDGES);               // 2N
    int*   cursor  = deg + 2 * N_ENT;                        // 2N
    int*   counter = cursor + 2 * N_ENT;                     // 1 (+3 pad)
    int*   offs    = counter + 4;                            // 2N
    float* dinv    = (float*)(offs + 2 * N_ENT);             // 2N
    float* cvec    = dinv + 2 * N_ENT;                       // 128

    const int* rows = ei;
    const int* cols = ei + NUM_EDGES;

    hipMemsetAsync(deg, 0, (4ull * N_ENT + 4) * sizeof(int), stream);

    deg_kernel<<<(NUM_EDGES + 255) / 256, 256, 0, stream>>>(rows, deg);
    dinv_kernel<<<(2 * N_ENT + 255) / 256, 256, 0, stream>>>(deg, dinv);
    offs_kernel<<<(2 * N_ENT + 255) / 256, 256, 0, stream>>>(deg, offs, counter);
    fill_kernel<<<(NUM_EDGES + 255) / 256, 256, 0, stream>>>(rows, cols, et, dinv, offs, cursor, recs);

    prep_x_kernel<<<(N_ENT * 16 + 255) / 256, 256, 0, stream>>>(x, (uint4*)xb);
    prep_wr_kernel<<<(8 * 12 * 64 + NUM_REL * 16 + 255) / 256, 256, 0, stream>>>(
        w_in, w_out, w_loop, r, (uint4*)wtf, (uint4*)rb16);
    cvec_kernel<<<1, 128, 0, stream>>>(loop_rel, w_loop, cvec);

    gather_agg_kernel<<<(2 * N_ENT * 16 + 255) / 256, 256, 0, stream>>>(
        offs, deg, recs, xb, rb16, (uint4*)aggf);

    mfma_gemm_kernel<<<(N_ENT + 127) / 128, 256, 0, stream>>>(
        (const uint4*)aggf, x, (const uint4*)wtf, bias, cvec, out);

    rel_gemm_kernel<<<NUM_REL, 128, 0, stream>>>(r, w_rel, r_out);
}

// Round 7
// 219.948 us; speedup vs baseline: 1.0994x; 1.0994x over previous
//
#include <hip/hip_runtime.h>
#include <hip/hip_bf16.h>

#define N_ENT    100000
#define NUM_REL  400
#define DIM      128
#define NUM_EDGES 800000
#define E_HALF   400000
#define N_RB     6250          // N_ENT/16 rowblocks

using short8 = __attribute__((ext_vector_type(8))) short;
using f32x4  = __attribute__((ext_vector_type(4))) float;

__device__ __forceinline__ float bf_lo(unsigned u) { return __uint_as_float(u << 16); }
__device__ __forceinline__ float bf_hi(unsigned u) { return __uint_as_float(u & 0xffff0000u); }
__device__ __forceinline__ unsigned short f2bf(float f) {
    unsigned u = __float_as_uint(f);
    u = u + 0x7fffu + ((u >> 16) & 1u);   // RNE
    return (unsigned short)(u >> 16);
}
__device__ __forceinline__ unsigned pack2bf(float a, float b) {
    return (unsigned)f2bf(a) | ((unsigned)f2bf(b) << 16);
}

// ---------------- deg histogram ----------------
__global__ __launch_bounds__(256) void deg_kernel(const int* __restrict__ rows,
                                                  int* __restrict__ deg) {
    int e = blockIdx.x * 256 + threadIdx.x;
    if (e >= NUM_EDGES) return;
    int half = (e >= E_HALF) ? 1 : 0;
    atomicAdd(&deg[half * N_ENT + rows[e]], 1);
}

// ---------------- dinv + segment offsets (merged) ----------------
__global__ __launch_bounds__(256) void dinv_offs_kernel(const int* __restrict__ deg,
                                                        float* __restrict__ dinv,
                                                        int* __restrict__ offs,
                                                        int* __restrict__ counter) {
    int i = blockIdx.x * 256 + threadIdx.x;
    int lane = threadIdx.x & 63;
    int v = (i < 2 * N_ENT) ? deg[i] : 0;
    if (i < 2 * N_ENT) dinv[i] = (v > 0) ? rsqrtf((float)v) : 0.0f;
    int pre = v;
    #pragma unroll
    for (int d = 1; d < 64; d <<= 1) {
        int t = __shfl_up(pre, d);
        if (lane >= d) pre += t;
    }
    int total = __shfl(pre, 63);
    int base = 0;
    if (lane == 0) base = atomicAdd(counter, total);
    base = __shfl(base, 0);
    if (i < 2 * N_ENT) offs[i] = base + pre - v;
}

// ---------------- fill CSR records {col|t<<17, norm} ----------------
__global__ __launch_bounds__(256) void fill_kernel(const int* __restrict__ rows,
                                                   const int* __restrict__ cols,
                                                   const int* __restrict__ et,
                                                   const float* __restrict__ dinv,
                                                   const int* __restrict__ offs,
                                                   int* __restrict__ cursor,
                                                   uint2* __restrict__ recs) {
    int e = blockIdx.x * 256 + threadIdx.x;
    if (e >= NUM_EDGES) return;
    int half = (e >= E_HALF) ? 1 : 0;
    int g = half * N_ENT + rows[e];
    int col = cols[e];
    int t = et[e];
    int pos = atomicAdd(&cursor[g], 1);
    float norm = dinv[g] * dinv[half * N_ENT + col];
    recs[offs[g] + pos] = make_uint2((unsigned)col | ((unsigned)t << 17),
                                     __float_as_uint(norm));
}

// ---------------- consolidated prep: xb, wtfrag, rb16, cvec ----------------
// wtfrag u4 index: ((nblk*12 + kb)*64 + lane); lane=(ks*16+lr): n=nblk*16+lr, k=kb*32+ks*8+e
__global__ __launch_bounds__(256) void prep_kernel(const float* __restrict__ x,
                                                   const float* __restrict__ w_in,
                                                   const float* __restrict__ w_out,
                                                   const float* __restrict__ w_loop,
                                                   const float* __restrict__ r,
                                                   const float* __restrict__ loop_rel,
                                                   uint4* __restrict__ xb4,
                                                   uint4* __restrict__ wtfrag,
                                                   uint4* __restrict__ rb16,
                                                   float* __restrict__ cvec) {
    if (blockIdx.x == gridDim.x - 1) {
        int j = threadIdx.x;
        if (j < 128) {
            float acc = 0.0f;
            #pragma unroll 8
            for (int k = 0; k < DIM; ++k)
                acc += loop_rel[k] * w_loop[k * DIM + j];
            cvec[j] = acc;
        }
        return;
    }
    int i = blockIdx.x * 256 + threadIdx.x;
    if (i < N_ENT * 16) {
        const float* p = x + (size_t)(i >> 4) * DIM + (i & 15) * 8;
        float4 f0 = *(const float4*)p;
        float4 f1 = *(const float4*)(p + 4);
        uint4 o;
        o.x = pack2bf(f0.x, f0.y);
        o.y = pack2bf(f0.z, f0.w);
        o.z = pack2bf(f1.x, f1.y);
        o.w = pack2bf(f1.z, f1.w);
        xb4[i] = o;
        return;
    }
    int j = i - N_ENT * 16;
    if (j < 8 * 12 * 64) {
        int lane = j & 63;
        int kb = (j >> 6) % 12;
        int nblk = j / 768;
        int n = nblk * 16 + (lane & 15);
        int s = kb >> 2;
        int klo = (kb & 3) * 32 + (lane >> 4) * 8;    // 0..127 within slice
        const float* W = (s == 0) ? w_in : (s == 1) ? w_out : w_loop;
        float v[8];
        #pragma unroll
        for (int e = 0; e < 8; ++e) v[e] = W[(klo + e) * DIM + n];
        uint4 o;
        o.x = pack2bf(v[0], v[1]);
        o.y = pack2bf(v[2], v[3]);
        o.z = pack2bf(v[4], v[5]);
        o.w = pack2bf(v[6], v[7]);
        wtfrag[j] = o;
        return;
    }
    int k = j - 8 * 12 * 64;
    if (k < NUM_REL * 16) {
        const float* p = r + (size_t)(k >> 4) * DIM + (k & 15) * 8;
        float4 f0 = *(const float4*)p;
        float4 f1 = *(const float4*)(p + 4);
        uint4 o;
        o.x = pack2bf(f0.x, f0.y);
        o.y = pack2bf(f0.z, f0.w);
        o.z = pack2bf(f1.x, f1.y);
        o.w = pack2bf(f1.z, f1.w);
        rb16[k] = o;
    }
}

// ---------------- gather-aggregate -> aggfrag (MFMA fragment order) ----------------
#define ACC8(X, V, NRM)                                        \
    acc[0] += (NRM) * (bf_lo((X).x) - bf_lo((V).x));           \
    acc[1] += (NRM) * (bf_hi((X).x) - bf_hi((V).x));           \
    acc[2] += (NRM) * (bf_lo((X).y) - bf_lo((V).y));           \
    acc[3] += (NRM) * (bf_hi((X).y) - bf_hi((V).y));           \
    acc[4] += (NRM) * (bf_lo((X).z) - bf_lo((V).z));           \
    acc[5] += (NRM) * (bf_hi((X).z) - bf_hi((V).z));           \
    acc[6] += (NRM) * (bf_lo((X).w) - bf_lo((V).w));           \
    acc[7] += (NRM) * (bf_hi((X).w) - bf_hi((V).w));

__global__ __launch_bounds__(256) void gather_agg_kernel(const int* __restrict__ offs,
                                                         const int* __restrict__ deg,
                                                         const uint2* __restrict__ recs,
                                                         const unsigned short* __restrict__ xb,
                                                         const unsigned short* __restrict__ rb16,
                                                         uint4* __restrict__ aggfrag) {
    int gid = blockIdx.x * 256 + threadIdx.x;
    int g = gid >> 4;
    if (g >= 2 * N_ENT) return;
    int c = gid & 15;                    // lane covers 16 B = 8 bf16 (k = c*8..c*8+7)
    int e = offs[g];
    int end = e + deg[g];
    float acc[8] = {0.f, 0.f, 0.f, 0.f, 0.f, 0.f, 0.f, 0.f};
    for (; e + 4 <= end; e += 4) {
        uint2 r0 = recs[e];
        uint2 r1 = recs[e + 1];
        uint2 r2 = recs[e + 2];
        uint2 r3 = recs[e + 3];
        uint4 x0 = ((const uint4*)(xb + (size_t)(r0.x & 0x1ffff) * DIM))[c];
        uint4 v0 = ((const uint4*)(rb16 + (size_t)(r0.x >> 17) * DIM))[c];
        uint4 x1 = ((const uint4*)(xb + (size_t)(r1.x & 0x1ffff) * DIM))[c];
        uint4 v1 = ((const uint4*)(rb16 + (size_t)(r1.x >> 17) * DIM))[c];
        uint4 x2 = ((const uint4*)(xb + (size_t)(r2.x & 0x1ffff) * DIM))[c];
        uint4 v2 = ((const uint4*)(rb16 + (size_t)(r2.x >> 17) * DIM))[c];
        uint4 x3 = ((const uint4*)(xb + (size_t)(r3.x & 0x1ffff) * DIM))[c];
        uint4 v3 = ((const uint4*)(rb16 + (size_t)(r3.x >> 17) * DIM))[c];
        float n0 = __uint_as_float(r0.y);
        float n1 = __uint_as_float(r1.y);
        float n2 = __uint_as_float(r2.y);
        float n3 = __uint_as_float(r3.y);
        ACC8(x0, v0, n0)
        ACC8(x1, v1, n1)
        ACC8(x2, v2, n2)
        ACC8(x3, v3, n3)
    }
    for (; e < end; ++e) {
        uint2 rA = recs[e];
        uint4 xA = ((const uint4*)(xb + (size_t)(rA.x & 0x1ffff) * DIM))[c];
        uint4 vA = ((const uint4*)(rb16 + (size_t)(rA.x >> 17) * DIM))[c];
        float nA = __uint_as_float(rA.y);
        ACC8(xA, vA, nA)
    }
    uint4 o;
    o.x = pack2bf(acc[0], acc[1]);
    o.y = pack2bf(acc[2], acc[3]);
    o.z = pack2bf(acc[4], acc[5]);
    o.w = pack2bf(acc[6], acc[7]);
    // fragment-order store: rowblk=g>>4, kq=c>>2, ksub=c&3, lr=g&15
    aggfrag[(((g >> 4) * 4 + (c >> 2)) * 64) + (c & 3) * 16 + (g & 15)] = o;
}

// ---------------- MFMA GEMM, fragment-direct, 64 rows/block for occupancy ----------------
// out = tanh((aggA@Win + aggB@Wout + x@Wloop - cvec)/3 + bias)
// M=100000, N=128, K=384. 64 rows/block, 4 waves: wave = 32 rows x 64 cols.
__global__ __launch_bounds__(256, 5) void mfma_gemm_kernel(const uint4* __restrict__ aggfrag,
                                                           const unsigned short* __restrict__ xb,
                                                           const uint4* __restrict__ wtfrag,
                                                           const float* __restrict__ bias,
                                                           const float* __restrict__ cvec,
                                                           float* __restrict__ out) {
    int tid = threadIdx.x;
    int wave = tid >> 6;
    int lane = tid & 63;
    int wm = wave >> 1, wn = wave & 1;
    int lr = lane & 15;
    int ks = lane >> 4;                    // 0..3
    int rbb = blockIdx.x * 4 + wm * 2;     // rowblk base for this wave (2 rowblocks)

    f32x4 acc[2][4];
    #pragma unroll
    for (int mi = 0; mi < 2; ++mi)
        #pragma unroll
        for (int ni = 0; ni < 4; ++ni)
            acc[mi][ni] = (f32x4){0.f, 0.f, 0.f, 0.f};

    #pragma unroll
    for (int kb = 0; kb < 12; ++kb) {
        int s = kb >> 2, kq = kb & 3;
        short8 a[2], b[4];
        #pragma unroll
        for (int ni = 0; ni < 4; ++ni) {
            uint4 u = wtfrag[((wn * 4 + ni) * 12 + kb) * 64 + lane];
            b[ni] = *(short8*)&u;
        }
        #pragma unroll
        for (int mi = 0; mi < 2; ++mi) {
            int rb = rbb + mi;
            if (rb > N_RB - 1) rb = N_RB - 1;
            uint4 u;
            if (s < 2) {
                u = aggfrag[((size_t)(rb + s * N_RB) * 4 + kq) * 64 + lane];
            } else {
                int row = rb * 16 + lr;
                u = *(const uint4*)(xb + (size_t)row * DIM + kq * 32 + ks * 8);
            }
            a[mi] = *(short8*)&u;
        }
        #pragma unroll
        for (int mi = 0; mi < 2; ++mi)
            #pragma unroll
            for (int ni = 0; ni < 4; ++ni)
                acc[mi][ni] = __builtin_amdgcn_mfma_f32_16x16x32_bf16(a[mi], b[ni], acc[mi][ni], 0, 0, 0);
    }

    int col0 = wn * 64;
    int row0w = blockIdx.x * 64 + wm * 32;
    const float third = 1.0f / 3.0f;
    float bb[4];
    #pragma unroll
    for (int ni = 0; ni < 4; ++ni) {
        int col = col0 + ni * 16 + lr;
        bb[ni] = bias[col] - third * cvec[col];
    }

    #pragma unroll
    for (int mi = 0; mi < 2; ++mi) {
        #pragma unroll
        for (int reg = 0; reg < 4; ++reg) {
            int grow = row0w + mi * 16 + ks * 4 + reg;
            if (grow < N_ENT) {
                #pragma unroll
                for (int ni = 0; ni < 4; ++ni)
                    out[(size_t)grow * DIM + col0 + ni * 16 + lr] =
                        tanhf(acc[mi][ni][reg] * third + bb[ni]);
            }
        }
    }
}

// ---------------- r_out = r @ w_rel  (400x128 @ 128x128, f32) ----------------
__global__ __launch_bounds__(128) void rel_gemm_kernel(const float* __restrict__ r,
                                                       const float* __restrict__ w_rel,
                                                       float* __restrict__ r_out) {
    __shared__ float rrow[128];
    int i = blockIdx.x;
    int j = threadIdx.x;
    rrow[j] = r[i * DIM + j];
    __syncthreads();
    float acc = 0.0f;
    #pragma unroll 8
    for (int k = 0; k < DIM; ++k)
        acc += rrow[k] * w_rel[k * DIM + j];
    r_out[i * DIM + j] = acc;
}

extern "C" void kernel_launch(void* const* d_in, const int* in_sizes, int n_in,
                              void* d_out, int out_size, void* d_ws, size_t ws_size,
                              hipStream_t stream) {
    const float* x        = (const float*)d_in[0];
    const float* r        = (const float*)d_in[1];
    const int*   ei       = (const int*)d_in[2];   // [2][800000]: rows then cols
    const int*   et       = (const int*)d_in[3];
    const float* w_in     = (const float*)d_in[4];
    const float* w_out    = (const float*)d_in[5];
    const float* w_loop   = (const float*)d_in[6];
    const float* w_rel    = (const float*)d_in[7];
    const float* loop_rel = (const float*)d_in[8];
    const float* bias     = (const float*)d_in[9];

    float* out   = (float*)d_out;            // 100000*128
    float* r_out = out + (size_t)N_ENT * DIM;

    // -------- workspace layout --------
    unsigned short* aggf = (unsigned short*)d_ws;            // [2N*128] bf16 frag-order
    unsigned short* xb   = aggf + 2ull * N_ENT * DIM;        // [N][128] bf16 row-major
    unsigned short* wtf  = xb + (size_t)N_ENT * DIM;         // 8*12*64*8 bf16 frag-order
    unsigned short* rb16 = wtf + 8 * 12 * 64 * 8;            // [400][128] bf16
    uint2* recs = (uint2*)(rb16 + NUM_REL * DIM);            // 800k x 8 B
    int*   deg     = (int*)(recs + NUM_EDGES);               // 2N
    int*   cursor  = deg + 2 * N_ENT;                        // 2N
    int*   counter = cursor + 2 * N_ENT;                     // 1 (+3 pad)
    int*   offs    = counter + 4;                            // 2N
    float* dinv    = (float*)(offs + 2 * N_ENT);             // 2N
    float* cvec    = dinv + 2 * N_ENT;                       // 128

    const int* rows = ei;
    const int* cols = ei + NUM_EDGES;

    hipMemsetAsync(deg, 0, (4ull * N_ENT + 4) * sizeof(int), stream);

    // prep is independent of the CSR build — launch first
    int prep_items = N_ENT * 16 + 8 * 12 * 64 + NUM_REL * 16;
    prep_kernel<<<(prep_items + 255) / 256 + 1, 256, 0, stream>>>(
        x, w_in, w_out, w_loop, r, loop_rel, (uint4*)xb, (uint4*)wtf, (uint4*)rb16, cvec);

    deg_kernel<<<(NUM_EDGES + 255) / 256, 256, 0, stream>>>(rows, deg);
    dinv_offs_kernel<<<(2 * N_ENT + 255) / 256, 256, 0, stream>>>(deg, dinv, offs, counter);
    fill_kernel<<<(NUM_EDGES + 255) / 256, 256, 0, stream>>>(rows, cols, et, dinv, offs, cursor, recs);

    gather_agg_kernel<<<(2 * N_ENT * 16 + 255) / 256, 256, 0, stream>>>(
        offs, deg, recs, xb, rb16, (uint4*)aggf);

    mfma_gemm_kernel<<<(N_ENT + 63) / 64, 256, 0, stream>>>(
        (const uint4*)aggf, xb, (const uint4*)wtf, bias, cvec, out);

    rel_gemm_kernel<<<NUM_REL, 128, 0, stream>>>(r, w_rel, r_out);
}

// Round 8
// 211.495 us; speedup vs baseline: 1.1433x; 1.0400x over previous
//
#include <hip/hip_runtime.h>
#include <hip/hip_bf16.h>

#define N_ENT    100000
#define NUM_REL  400
#define DIM      128
#define NUM_EDGES 800000
#define E_HALF   400000
#define N_RB     6250          // N_ENT/16 rowblocks

using short8 = __attribute__((ext_vector_type(8))) short;
using f32x4  = __attribute__((ext_vector_type(4))) float;

__device__ __forceinline__ float bf_lo(unsigned u) { return __uint_as_float(u << 16); }
__device__ __forceinline__ float bf_hi(unsigned u) { return __uint_as_float(u & 0xffff0000u); }
__device__ __forceinline__ unsigned short f2bf(float f) {
    unsigned u = __float_as_uint(f);
    u = u + 0x7fffu + ((u >> 16) & 1u);   // RNE
    return (unsigned short)(u >> 16);
}
__device__ __forceinline__ unsigned pack2bf(float a, float b) {
    return (unsigned)f2bf(a) | ((unsigned)f2bf(b) << 16);
}

// ---------------- dinv + segment offsets (merged) ----------------
__global__ __launch_bounds__(256) void dinv_offs_kernel(const int* __restrict__ deg,
                                                        float* __restrict__ dinv,
                                                        int* __restrict__ offs,
                                                        int* __restrict__ counter) {
    int i = blockIdx.x * 256 + threadIdx.x;
    int lane = threadIdx.x & 63;
    int v = (i < 2 * N_ENT) ? deg[i] : 0;
    if (i < 2 * N_ENT) dinv[i] = (v > 0) ? rsqrtf((float)v) : 0.0f;
    int pre = v;
    #pragma unroll
    for (int d = 1; d < 64; d <<= 1) {
        int t = __shfl_up(pre, d);
        if (lane >= d) pre += t;
    }
    int total = __shfl(pre, 63);
    int base = 0;
    if (lane == 0) base = atomicAdd(counter, total);
    base = __shfl(base, 0);
    if (i < 2 * N_ENT) offs[i] = base + pre - v;
}

// ---------------- fill CSR records {col|t<<17, norm} ----------------
__global__ __launch_bounds__(256) void fill_kernel(const int* __restrict__ rows,
                                                   const int* __restrict__ cols,
                                                   const int* __restrict__ et,
                                                   const float* __restrict__ dinv,
                                                   const int* __restrict__ offs,
                                                   int* __restrict__ cursor,
                                                   uint2* __restrict__ recs) {
    int e = blockIdx.x * 256 + threadIdx.x;
    if (e >= NUM_EDGES) return;
    int half = (e >= E_HALF) ? 1 : 0;
    int g = half * N_ENT + rows[e];
    int col = cols[e];
    int t = et[e];
    int pos = atomicAdd(&cursor[g], 1);
    float norm = dinv[g] * dinv[half * N_ENT + col];
    recs[offs[g] + pos] = make_uint2((unsigned)col | ((unsigned)t << 17),
                                     __float_as_uint(norm));
}

// ---------------- mega-prep: xb, wtfrag, rb16, cvec, rel_gemm, deg histogram ----------------
// block ranges: [0,6250) xb | [6250,6274) wtfrag | [6274,6299) rb16 | [6299] cvec
//               [6300,6500) rel | [6500,9625) deg
#define PB_XB   6250
#define PB_WT   (PB_XB + 24)
#define PB_RB   (PB_WT + 25)
#define PB_CV   (PB_RB + 1)
#define PB_REL  (PB_CV + 200)
#define PB_DEG  (PB_REL + 3125)
__global__ __launch_bounds__(256) void prep_kernel(const float* __restrict__ x,
                                                   const float* __restrict__ w_in,
                                                   const float* __restrict__ w_out,
                                                   const float* __restrict__ w_loop,
                                                   const float* __restrict__ r,
                                                   const float* __restrict__ loop_rel,
                                                   const float* __restrict__ w_rel,
                                                   const int* __restrict__ rows,
                                                   uint4* __restrict__ xb4,
                                                   uint4* __restrict__ wtfrag,
                                                   uint4* __restrict__ rb16,
                                                   float* __restrict__ cvec,
                                                   float* __restrict__ r_out,
                                                   int* __restrict__ deg) {
    int b = blockIdx.x;
    int t = threadIdx.x;
    if (b < PB_XB) {
        int i = b * 256 + t;
        if (i < N_ENT * 16) {
            const float* p = x + (size_t)(i >> 4) * DIM + (i & 15) * 8;
            float4 f0 = *(const float4*)p;
            float4 f1 = *(const float4*)(p + 4);
            uint4 o;
            o.x = pack2bf(f0.x, f0.y);
            o.y = pack2bf(f0.z, f0.w);
            o.z = pack2bf(f1.x, f1.y);
            o.w = pack2bf(f1.z, f1.w);
            xb4[i] = o;
        }
    } else if (b < PB_WT) {
        int j = (b - PB_XB) * 256 + t;
        if (j < 8 * 12 * 64) {
            int lane = j & 63;
            int kb = (j >> 6) % 12;
            int nblk = j / 768;
            int n = nblk * 16 + (lane & 15);
            int s = kb >> 2;
            int klo = (kb & 3) * 32 + (lane >> 4) * 8;    // 0..127 within slice
            const float* W = (s == 0) ? w_in : (s == 1) ? w_out : w_loop;
            float v[8];
            #pragma unroll
            for (int e = 0; e < 8; ++e) v[e] = W[(klo + e) * DIM + n];
            uint4 o;
            o.x = pack2bf(v[0], v[1]);
            o.y = pack2bf(v[2], v[3]);
            o.z = pack2bf(v[4], v[5]);
            o.w = pack2bf(v[6], v[7]);
            wtfrag[j] = o;
        }
    } else if (b < PB_RB) {
        int k = (b - PB_WT) * 256 + t;
        if (k < NUM_REL * 16) {
            const float* p = r + (size_t)(k >> 4) * DIM + (k & 15) * 8;
            float4 f0 = *(const float4*)p;
            float4 f1 = *(const float4*)(p + 4);
            uint4 o;
            o.x = pack2bf(f0.x, f0.y);
            o.y = pack2bf(f0.z, f0.w);
            o.z = pack2bf(f1.x, f1.y);
            o.w = pack2bf(f1.z, f1.w);
            rb16[k] = o;
        }
    } else if (b < PB_CV) {
        if (t < 128) {
            float acc = 0.0f;
            #pragma unroll 8
            for (int k = 0; k < DIM; ++k)
                acc += loop_rel[k] * w_loop[k * DIM + t];
            cvec[t] = acc;
        }
    } else if (b < PB_REL) {
        int row = (b - PB_CV) * 2 + (t >> 7);
        int col = t & 127;
        const float* rr = r + (size_t)row * DIM;
        float acc = 0.0f;
        #pragma unroll 8
        for (int k = 0; k < DIM; ++k)
            acc += rr[k] * w_rel[k * DIM + col];
        r_out[(size_t)row * DIM + col] = acc;
    } else {
        int e = (b - PB_REL) * 256 + t;
        if (e < NUM_EDGES) {
            int half = (e >= E_HALF) ? 1 : 0;
            atomicAdd(&deg[half * N_ENT + rows[e]], 1);
        }
    }
}

// ---------------- gather-aggregate -> aggfrag (MFMA fragment order) ----------------
#define ACC8(X, V, NRM)                                        \
    acc[0] += (NRM) * (bf_lo((X).x) - bf_lo((V).x));           \
    acc[1] += (NRM) * (bf_hi((X).x) - bf_hi((V).x));           \
    acc[2] += (NRM) * (bf_lo((X).y) - bf_lo((V).y));           \
    acc[3] += (NRM) * (bf_hi((X).y) - bf_hi((V).y));           \
    acc[4] += (NRM) * (bf_lo((X).z) - bf_lo((V).z));           \
    acc[5] += (NRM) * (bf_hi((X).z) - bf_hi((V).z));           \
    acc[6] += (NRM) * (bf_lo((X).w) - bf_lo((V).w));           \
    acc[7] += (NRM) * (bf_hi((X).w) - bf_hi((V).w));

__global__ __launch_bounds__(256) void gather_agg_kernel(const int* __restrict__ offs,
                                                         const int* __restrict__ deg,
                                                         const uint2* __restrict__ recs,
                                                         const unsigned short* __restrict__ xb,
                                                         const unsigned short* __restrict__ rb16,
                                                         uint4* __restrict__ aggfrag) {
    int gid = blockIdx.x * 256 + threadIdx.x;
    int g = gid >> 4;
    if (g >= 2 * N_ENT) return;
    int c = gid & 15;                    // lane covers 16 B = 8 bf16 (k = c*8..c*8+7)
    int e = offs[g];
    int end = e + deg[g];
    float acc[8] = {0.f, 0.f, 0.f, 0.f, 0.f, 0.f, 0.f, 0.f};
    for (; e + 4 <= end; e += 4) {
        uint2 r0 = recs[e];
        uint2 r1 = recs[e + 1];
        uint2 r2 = recs[e + 2];
        uint2 r3 = recs[e + 3];
        uint4 x0 = ((const uint4*)(xb + (size_t)(r0.x & 0x1ffff) * DIM))[c];
        uint4 v0 = ((const uint4*)(rb16 + (size_t)(r0.x >> 17) * DIM))[c];
        uint4 x1 = ((const uint4*)(xb + (size_t)(r1.x & 0x1ffff) * DIM))[c];
        uint4 v1 = ((const uint4*)(rb16 + (size_t)(r1.x >> 17) * DIM))[c];
        uint4 x2 = ((const uint4*)(xb + (size_t)(r2.x & 0x1ffff) * DIM))[c];
        uint4 v2 = ((const uint4*)(rb16 + (size_t)(r2.x >> 17) * DIM))[c];
        uint4 x3 = ((const uint4*)(xb + (size_t)(r3.x & 0x1ffff) * DIM))[c];
        uint4 v3 = ((const uint4*)(rb16 + (size_t)(r3.x >> 17) * DIM))[c];
        float n0 = __uint_as_float(r0.y);
        float n1 = __uint_as_float(r1.y);
        float n2 = __uint_as_float(r2.y);
        float n3 = __uint_as_float(r3.y);
        ACC8(x0, v0, n0)
        ACC8(x1, v1, n1)
        ACC8(x2, v2, n2)
        ACC8(x3, v3, n3)
    }
    for (; e < end; ++e) {
        uint2 rA = recs[e];
        uint4 xA = ((const uint4*)(xb + (size_t)(rA.x & 0x1ffff) * DIM))[c];
        uint4 vA = ((const uint4*)(rb16 + (size_t)(rA.x >> 17) * DIM))[c];
        float nA = __uint_as_float(rA.y);
        ACC8(xA, vA, nA)
    }
    uint4 o;
    o.x = pack2bf(acc[0], acc[1]);
    o.y = pack2bf(acc[2], acc[3]);
    o.z = pack2bf(acc[4], acc[5]);
    o.w = pack2bf(acc[6], acc[7]);
    // fragment-order store: rowblk=g>>4, kq=c>>2, ksub=c&3, lr=g&15
    aggfrag[(((g >> 4) * 4 + (c >> 2)) * 64) + (c & 3) * 16 + (g & 15)] = o;
}

// ---------------- MFMA GEMM, fragment-direct, depth-1 register prefetch ----------------
// out = tanh((aggA@Win + aggB@Wout + x@Wloop - cvec)/3 + bias)
// M=100000, N=128, K=384. 64 rows/block, 4 waves: wave = 32 rows x 64 cols.
__global__ __launch_bounds__(256) void mfma_gemm_kernel(const uint4* __restrict__ aggfrag,
                                                        const unsigned short* __restrict__ xb,
                                                        const uint4* __restrict__ wtfrag,
                                                        const float* __restrict__ bias,
                                                        const float* __restrict__ cvec,
                                                        float* __restrict__ out) {
    int tid = threadIdx.x;
    int wave = tid >> 6;
    int lane = tid & 63;
    int wm = wave >> 1, wn = wave & 1;
    int lr = lane & 15;
    int ks = lane >> 4;                    // 0..3
    int rbb = blockIdx.x * 4 + wm * 2;     // rowblk base for this wave (2 rowblocks)

    f32x4 acc[2][4];
    #pragma unroll
    for (int mi = 0; mi < 2; ++mi)
        #pragma unroll
        for (int ni = 0; ni < 4; ++ni)
            acc[mi][ni] = (f32x4){0.f, 0.f, 0.f, 0.f};

    int rbc[2];
    #pragma unroll
    for (int mi = 0; mi < 2; ++mi) {
        int rb = rbb + mi;
        rbc[mi] = (rb > N_RB - 1) ? (N_RB - 1) : rb;
    }

    auto LOADB = [&](int kb, short8* b) {
        #pragma unroll
        for (int ni = 0; ni < 4; ++ni) {
            uint4 u = wtfrag[((wn * 4 + ni) * 12 + kb) * 64 + lane];
            b[ni] = *(short8*)&u;
        }
    };
    auto LOADA = [&](int kb, short8* a) {
        int s = kb >> 2, kq = kb & 3;
        #pragma unroll
        for (int mi = 0; mi < 2; ++mi) {
            uint4 u;
            if (s < 2) {
                u = aggfrag[((size_t)(rbc[mi] + s * N_RB) * 4 + kq) * 64 + lane];
            } else {
                int row = rbc[mi] * 16 + lr;
                u = *(const uint4*)(xb + (size_t)row * DIM + kq * 32 + ks * 8);
            }
            a[mi] = *(short8*)&u;
        }
    };
    auto MF = [&](short8* a, short8* b) {
        #pragma unroll
        for (int mi = 0; mi < 2; ++mi)
            #pragma unroll
            for (int ni = 0; ni < 4; ++ni)
                acc[mi][ni] = __builtin_amdgcn_mfma_f32_16x16x32_bf16(a[mi], b[ni], acc[mi][ni], 0, 0, 0);
    };

    short8 A0[2], B0[4], A1[2], B1[4];
    LOADA(0, A0); LOADB(0, B0);
    #pragma unroll
    for (int kb = 0; kb < 12; kb += 2) {
        LOADA(kb + 1, A1); LOADB(kb + 1, B1);   // prefetch next while computing current
        MF(A0, B0);
        if (kb + 2 < 12) { LOADA(kb + 2, A0); LOADB(kb + 2, B0); }
        MF(A1, B1);
    }

    int col0 = wn * 64;
    int row0w = blockIdx.x * 64 + wm * 32;
    const float third = 1.0f / 3.0f;
    float bb[4];
    #pragma unroll
    for (int ni = 0; ni < 4; ++ni) {
        int col = col0 + ni * 16 + lr;
        bb[ni] = bias[col] - third * cvec[col];
    }

    #pragma unroll
    for (int mi = 0; mi < 2; ++mi) {
        #pragma unroll
        for (int reg = 0; reg < 4; ++reg) {
            int grow = row0w + mi * 16 + ks * 4 + reg;
            if (grow < N_ENT) {
                #pragma unroll
                for (int ni = 0; ni < 4; ++ni)
                    out[(size_t)grow * DIM + col0 + ni * 16 + lr] =
                        tanhf(acc[mi][ni][reg] * third + bb[ni]);
            }
        }
    }
}

extern "C" void kernel_launch(void* const* d_in, const int* in_sizes, int n_in,
                              void* d_out, int out_size, void* d_ws, size_t ws_size,
                              hipStream_t stream) {
    const float* x        = (const float*)d_in[0];
    const float* r        = (const float*)d_in[1];
    const int*   ei       = (const int*)d_in[2];   // [2][800000]: rows then cols
    const int*   et       = (const int*)d_in[3];
    const float* w_in     = (const float*)d_in[4];
    const float* w_out    = (const float*)d_in[5];
    const float* w_loop   = (const float*)d_in[6];
    const float* w_rel    = (const float*)d_in[7];
    const float* loop_rel = (const float*)d_in[8];
    const float* bias     = (const float*)d_in[9];

    float* out   = (float*)d_out;            // 100000*128
    float* r_out = out + (size_t)N_ENT * DIM;

    // -------- workspace layout --------
    unsigned short* aggf = (unsigned short*)d_ws;            // [2N*128] bf16 frag-order
    unsigned short* xb   = aggf + 2ull * N_ENT * DIM;        // [N][128] bf16 row-major
    unsigned short* wtf  = xb + (size_t)N_ENT * DIM;         // 8*12*64*8 bf16 frag-order
    unsigned short* rb16 = wtf + 8 * 12 * 64 * 8;            // [400][128] bf16
    uint2* recs = (uint2*)(rb16 + NUM_REL * DIM);            // 800k x 8 B
    int*   deg     = (int*)(recs + NUM_EDGES);               // 2N
    int*   cursor  = deg + 2 * N_ENT;                        // 2N
    int*   counter = cursor + 2 * N_ENT;                     // 1 (+3 pad)
    int*   offs    = counter + 4;                            // 2N
    float* dinv    = (float*)(offs + 2 * N_ENT);             // 2N
    float* cvec    = dinv + 2 * N_ENT;                       // 128

    const int* rows = ei;
    const int* cols = ei + NUM_EDGES;

    hipMemsetAsync(deg, 0, (4ull * N_ENT + 4) * sizeof(int), stream);

    prep_kernel<<<PB_DEG, 256, 0, stream>>>(
        x, w_in, w_out, w_loop, r, loop_rel, w_rel, rows,
        (uint4*)xb, (uint4*)wtf, (uint4*)rb16, cvec, r_out, deg);

    dinv_offs_kernel<<<(2 * N_ENT + 255) / 256, 256, 0, stream>>>(deg, dinv, offs, counter);
    fill_kernel<<<(NUM_EDGES + 255) / 256, 256, 0, stream>>>(rows, cols, et, dinv, offs, cursor, recs);

    gather_agg_kernel<<<(2 * N_ENT * 16 + 255) / 256, 256, 0, stream>>>(
        offs, deg, recs, xb, rb16, (uint4*)aggf);

    mfma_gemm_kernel<<<(N_ENT + 63) / 64, 256, 0, stream>>>(
        (const uint4*)aggf, xb, (const uint4*)wtf, bias, cvec, out);
}